// Round 16
// baseline (177.041 us; speedup 1.0000x reference)
//
#include <hip/hip_runtime.h>
#include <hip/hip_bf16.h>

// CARAFE fp32 pipeline. x(4,256,64,64), Wc(64,256), bc(64), We(100,64,3,3),
// be(100) -> out(4,256,128,128). SF=2 K=5 G=1 CC=64 EK=3. All I/O fp32.
//
// ws layout (fp32 elements):
//   comp  [4][64][66*66]   zero-padded halo   @ 0          (1,115,136)
//   Wr2   [ij4][kt5][cc64][48]  q*5+kk packed @ 1,115,136  (61,440 of 64,512)
//   logit [tile256][e100][off64]  TILE-MAJOR  @ 1,179,648  (1,638,400)
//     tile = n*64 + th*8 + tw (8x8-px k2 tiles), off = (h&7)*8 + (w&7).
//     NB: first 16,384 floats double as WcT[c256][cc64] during k0->k1
//     (k2 overwrites tiles 0..2 later; stream-serialized).
// total 11,272,192 B. Host-gated on ws_size; fallback = fused kernel.
//
// Round 19 (this round): k2 occupancy A/B. r15 counters: occ 41%, VALU 45%,
// HBM 5%, conflicts ~0 -- latency-bound with ~55% un-hidden. The one knob
// never turned in isolation: blocks/CU via LDS. compT stride 12->10 (halo
// is exactly 10x10): 30720B -> 25600B = 6 blocks/CU (24 waves, was 20).
// Bank check: per-phase (py*10+pxx)%32 worst 2-way = free; staging uses
// e%100 directly. ZERO other changes. If k2 doesn't move, it is per-wave
// ILP-bound -> structural floor; plateau declared next round.

#define COMP_F 0
#define WR_F   1115136
#define LOG_F  1179648
#define WS_NEED 11272192ull
#define CSTR 4356  // 66*66 comp per-channel stride

// ---------------- K0: Wr2 repack + WcT transpose ------------------------
// job1 (tid < 57600): We(100,576) -> Wr2[ij][kt][cc][48], row = q*5+kk.
// job2 (tid >= 57600): Wc(64,256) -> WcT[c][cc] @ LOG_F (16,384 floats).
__global__ void k0_wr(const float* __restrict__ We, const float* __restrict__ Wc,
                      float* __restrict__ ws) {
    int tid = blockIdx.x * blockDim.x + threadIdx.x;
    if (tid < 57600) {
        int kk = tid % 5;
        int q  = (tid / 5) % 9;
        int cc = (tid / 45) % 64;
        int kt = (tid / 2880) % 5;
        int ij = tid / 14400;
        ws[WR_F + (size_t)(((ij * 5 + kt) * 64 + cc)) * 48 + q * 5 + kk] =
            We[(size_t)(4 * (kt * 5 + kk) + ij) * 576 + cc * 9 + q];
    } else if (tid < 57600 + 16384) {
        int t2 = tid - 57600;
        int c = t2 >> 6, cc = t2 & 63;
        ws[LOG_F + t2] = Wc[cc * 256 + c];
    }
}

// ---------------- K1 v4: 1x1 compressor 256->64, padded comp out --------
// grid 512 = ccq*64 + pxtile; block 256thr; thread = one pixel, 8 cc.
// Weights from WcT via s_load_dwordx8 (restrict args). Coalesced x loads.
__global__ __launch_bounds__(256) void k1_comp(const float* __restrict__ x,
                                               const float* __restrict__ bc,
                                               const float* __restrict__ wT,
                                               float* __restrict__ comp) {
    int b      = blockIdx.x;
    int pxtile = b & 63;       // 0..63 ; b%8 = pxtile%8 -> cc-siblings same XCD
    int ccq    = b >> 6;       // 0..7, wave-uniform
    int tid = threadIdx.x;
    int n   = pxtile >> 4;
    int off = (pxtile & 15) * 256 + tid;   // 0..4095 within image
    int h = off >> 6, w = off & 63;
    int cc0 = ccq * 8;

    const float* xp = x + (size_t)n * 256 * 4096 + off;

    float acc[8];
#pragma unroll
    for (int u = 0; u < 8; ++u) acc[u] = 0.f;

#pragma unroll 8
    for (int c = 0; c < 256; ++c) {
        float xv = xp[(size_t)c * 4096];
        const float* wr = wT + c * 64 + cc0;   // uniform -> s_load_dwordx8
#pragma unroll
        for (int u = 0; u < 8; ++u) acc[u] += xv * wr[u];
    }

    float* compb = comp + (size_t)(n * 64 + cc0) * CSTR;
#pragma unroll
    for (int u = 0; u < 8; ++u) {
        float* cb_ = compb + (size_t)u * CSTR;
        cb_[(h + 1) * 66 + (w + 1)] = acc[u] + bc[cc0 + u];
        // zero halo border (pad=1 of the 3x3 conv)
        if (w < 2) cb_[(h + 1) * 66 + (w ? 65 : 0)] = 0.f;
        if (h == 0)  { cb_[w] = 0.f;           if (w < 2) cb_[64 + w] = 0.f; }
        if (h == 63) { cb_[65 * 66 + w] = 0.f; if (w < 2) cb_[65 * 66 + 64 + w] = 0.f; }
    }
}

// ---------------- K2 v12: 3x3 encoder, 6 blocks/CU ----------------------
// = v11 (2-channel drain amortization, conflict-free lane map, SGPR
// weights, tile-major coalesced stores, grid 1280) with compT row stride
// 12 -> 10: LDS 25600B -> 6 blocks/CU = 24 waves/CU (was 5/20). Banks:
// per-phase (py*10+pxx)%32 worst 2-way (free, m136-measured).
#define K2RS 10   // compT row stride (words)
#define K2CS 100  // per-channel stride = 10 rows x 10
__global__ __launch_bounds__(256, 5) void k2_enc(const float* __restrict__ be,
                                                 const float* __restrict__ comp,
                                                 const float* __restrict__ wr,
                                                 float* __restrict__ logits) {
    __shared__ __align__(16) float compT[64 * K2CS];  // 25600 B
    int b    = blockIdx.x;
    int tile = b & 255;                              // = n*64 + th*8 + tw
    int kt   = b >> 8;                               // 0..4, siblings same XCD
    int n = tile >> 6, th = (tile >> 3) & 7, tw = tile & 7;
    int h0 = th * 8, w0 = tw * 8;
    int tid = threadIdx.x;

    const float* compn = comp + (size_t)n * 64 * CSTR;
    // stage comp halo tile: compT[c*100 + rq] = comp[c][h0 + rq/10][w0 + rq%10]
    for (int e = tid; e < 6400; e += 256) {
        int c = e / 100, rq = e % 100;
        compT[c * K2CS + rq] =
            compn[(size_t)c * CSTR + (h0 + rq / 10) * 66 + (w0 + rq % 10)];
    }
    __syncthreads();

    int lane = tid & 63;
    int ij   = __builtin_amdgcn_readfirstlane(tid >> 6);  // force scalar
    int py = lane & 7, pxx = lane >> 3;   // conflict-free bank walk (r13)

    const float* wb = wr + (size_t)((ij * 5 + kt) * 64) * 48;

    float accA[5], accB[5];
#pragma unroll
    for (int kk = 0; kk < 5; ++kk) {
        accA[kk] = be[4 * (kt * 5 + kk) + ij];
        accB[kk] = 0.f;
    }

    for (int c = 0; c < 64; c += 2) {
        const float* cp = compT + c * K2CS + py * K2RS + pxx;
        float cv0[9], cv1[9];
#pragma unroll
        for (int dy = 0; dy < 3; ++dy)
#pragma unroll
            for (int dx = 0; dx < 3; ++dx) {
                cv0[dy * 3 + dx] = cp[dy * K2RS + dx];
                cv1[dy * 3 + dx] = cp[K2CS + dy * K2RS + dx];
            }
        const float* w0 = wb + c * 48;               // uniform -> s_load
        const float* w1 = w0 + 48;
#pragma unroll
        for (int q = 0; q < 9; ++q) {
            float v0 = cv0[q], v1 = cv1[q];
#pragma unroll
            for (int kk = 0; kk < 5; ++kk) {
                accA[kk] += v0 * w0[q * 5 + kk];     // v_fmac v, s, v
                accB[kk] += v1 * w1[q * 5 + kk];
            }
        }
    }

    // tile-major store: one contiguous 256B block per e-plane.
    float* lp = logits + (size_t)tile * 6400 + (py * 8 + pxx);
#pragma unroll
    for (int kk = 0; kk < 5; ++kk)
        lp[(4 * (kt * 5 + kk) + ij) * 64] = accA[kk] + accB[kk];
}

// ---------------- K2s v4: in-place softmax, tile-major ------------------
// grid 256 x 256thr: block = one 8x8 tile (6400 contiguous floats).
// Coalesced float4 stage/unstage. Thread = (ij = tid>>6, off = tid&63):
// reads L[(4k+ij)*64 + off] stride 256 -> 2-way alias = free.
__global__ __launch_bounds__(256) void k2s_sm(float* __restrict__ logits) {
    __shared__ __align__(16) float L[6400];  // 25600 B
    float* gp = logits + (size_t)blockIdx.x * 6400;
    int tid = threadIdx.x;

    for (int e4 = tid; e4 < 1600; e4 += 256)
        ((float4*)L)[e4] = ((const float4*)gp)[e4];
    __syncthreads();

    int ij = tid >> 6, off = tid & 63;
    float* p = L + ij * 64 + off;
    float m[25];
#pragma unroll
    for (int k = 0; k < 25; ++k) m[k] = p[k * 256];
    float mx = m[0];
#pragma unroll
    for (int k = 1; k < 25; ++k) mx = fmaxf(mx, m[k]);
    float ss = 0.f;
#pragma unroll
    for (int k = 0; k < 25; ++k) { m[k] = __expf(m[k] - mx); ss += m[k]; }
    float inv = 1.f / ss;
#pragma unroll
    for (int k = 0; k < 25; ++k) p[k * 256] = m[k] * inv;
    __syncthreads();

    for (int e4 = tid; e4 < 1600; e4 += 256)
        ((float4*)gp)[e4] = ((const float4*)L)[e4];
}

// ---------------- K3 v5: reassembly, tile-major mask reads --------------
// grid 1024 x 256thr: b = cchunk*64 + tile16. 16x16 px tile, 16-c chunk.
// Masks: per tap, 4 scalar loads at mbase[(4t+ij)*64] (2x128B segments
// per wave-load). x tile in LDS as [cg8][r20][q20][2] (unchanged).
__global__ __launch_bounds__(256) void k3_out(const float* __restrict__ x,
                                              const float* __restrict__ logits,
                                              float* __restrict__ out) {
    __shared__ __align__(16) float xt[8 * 20 * 42];  // 26880 B
    int b      = blockIdx.x;
    int tile16 = b & 63;
    int cchunk = b >> 6;
    int n = tile16 >> 4, ty0 = ((tile16 >> 2) & 3) * 16, tx0 = (tile16 & 3) * 16;
    int c0 = cchunk * 16;

    int py = threadIdx.x >> 4, pxx = threadIdx.x & 15;
    int h = ty0 + py, w = tx0 + pxx;

    // stage x halo tile as float2 (halo col origin tx0-2 is even -> the
    // 20-wide row is 10 aligned float2s, all-or-nothing in bounds).
    const float* xn = x + (size_t)(n * 256 + c0) * 4096;
    for (int e2 = threadIdx.x; e2 < 3200; e2 += 256) {
        int c = e2 / 200, rem = e2 % 200, r = rem / 10, q2 = rem % 10;
        int hh = ty0 + r - 2, ww = tx0 + 2 * q2 - 2;
        float2 v = {0.f, 0.f};
        if (hh >= 0 && hh < 64 && ww >= 0 && ww < 64)
            v = *(const float2*)(xn + (size_t)c * 4096 + hh * 64 + ww);
        int a0 = (c >> 1) * 840 + r * 42 + 4 * q2 + (c & 1);
        xt[a0]     = v.x;
        xt[a0 + 2] = v.y;
    }
    __syncthreads();

    // tile-major mask base for this thread's pixel
    int tileIdx = n * 64 + ((ty0 >> 3) + (py >> 3)) * 8 + (tx0 >> 3) + (pxx >> 3);
    int off     = (py & 7) * 8 + (pxx & 7);
    const float* mbase = logits + (size_t)tileIdx * 6400 + off;
    const float* vb = xt + py * 42 + pxx * 2;

    float2 A[8][4];
#pragma unroll
    for (int cg = 0; cg < 8; ++cg)
#pragma unroll
        for (int u = 0; u < 4; ++u) A[cg][u] = {0.f, 0.f};

    for (int dy = 0; dy < 5; ++dy) {
        const float* vrow = vb + dy * 42;
#pragma unroll
        for (int dx = 0; dx < 5; ++dx) {
            int t = dy * 5 + dx;
            const float* mp = mbase + 4 * t * 64;
            float4 mk = {mp[0], mp[64], mp[128], mp[192]};  // 4 coalesced scalars
#pragma unroll
            for (int cg = 0; cg < 8; ++cg) {
                float2 v = *(const float2*)(vrow + cg * 840 + dx * 2);
                A[cg][0].x += v.x * mk.x; A[cg][0].y += v.y * mk.x;
                A[cg][1].x += v.x * mk.y; A[cg][1].y += v.y * mk.y;
                A[cg][2].x += v.x * mk.z; A[cg][2].y += v.y * mk.z;
                A[cg][3].x += v.x * mk.w; A[cg][3].y += v.y * mk.w;
            }
        }
    }

#pragma unroll
    for (int cg = 0; cg < 8; ++cg) {
        int c = cg * 2;
        size_t ob0 = (((size_t)(n * 256 + c0 + c) * 128) + 2 * h) * 128 + 2 * w;
        float2 r0 = {A[cg][0].x, A[cg][1].x}, r1 = {A[cg][2].x, A[cg][3].x};
        *(float2*)(out + ob0)       = r0;
        *(float2*)(out + ob0 + 128) = r1;
        size_t ob1 = ob0 + 16384;
        float2 r2 = {A[cg][0].y, A[cg][1].y}, r3 = {A[cg][2].y, A[cg][3].y};
        *(float2*)(out + ob1)       = r2;
        *(float2*)(out + ob1 + 128) = r3;
    }
}

// ---------------- Fallback: fused kernel, fp32-only ---------------------
__global__ __launch_bounds__(256) void k_fused(const float* __restrict__ x,
                                               const float* __restrict__ Wc,
                                               const float* __restrict__ bc,
                                               const float* __restrict__ We,
                                               const float* __restrict__ be,
                                               float* __restrict__ out) {
    __shared__ float compS[64 * 101];
    int n = blockIdx.x >> 6, tile = blockIdx.x & 63;
    int ty0 = (tile >> 3) * 8, tx0 = (tile & 7) * 8;
    const float* xn = x + (size_t)n * 256 * 4096;
    {
        int pa = threadIdx.x & 127;
        int ga = __builtin_amdgcn_readfirstlane(threadIdx.x >> 7);
        bool act = pa < 100;
        int ah = ty0 + pa / 10 - 1, aw = tx0 + pa % 10 - 1;
        bool inb = act && ah >= 0 && ah < 64 && aw >= 0 && aw < 64;
        int xoff = ah * 64 + aw;
        float acc[32];
#pragma unroll
        for (int i = 0; i < 32; ++i) acc[i] = 0.f;
        for (int c = 0; c < 256; ++c) {
            float xv = inb ? xn[(size_t)c * 4096 + xoff] : 0.f;
#pragma unroll
            for (int i = 0; i < 32; ++i) acc[i] += xv * Wc[(ga * 32 + i) * 256 + c];
        }
        if (act)
#pragma unroll
            for (int i = 0; i < 32; ++i) {
                int cc = ga * 32 + i;
                compS[cc * 101 + pa] = inb ? acc[i] + bc[cc] : 0.f;
            }
    }
    __syncthreads();
    int px = threadIdx.x & 63;
    int ij = __builtin_amdgcn_readfirstlane(threadIdx.x >> 6);
    int py = px >> 3, pxx = px & 7;
    int h = ty0 + py, w = tx0 + pxx;
    float m[25];
#pragma unroll
    for (int k = 0; k < 25; ++k) m[k] = be[4 * k + ij];
    for (int cc = 0; cc < 64; ++cc) {
        float cv[9];
#pragma unroll
        for (int dy = 0; dy < 3; ++dy)
#pragma unroll
            for (int dx = 0; dx < 3; ++dx)
                cv[dy * 3 + dx] = compS[cc * 101 + (py + dy) * 10 + (pxx + dx)];
        int base = cc * 9;
#pragma unroll
        for (int k = 0; k < 25; ++k) {
            int eb = (4 * k + ij) * 576 + base;
            float s = 0.f;
#pragma unroll
            for (int qb = 0; qb < 9; ++qb) s += cv[qb] * We[eb + qb];
            m[k] += s;
        }
    }
    float mxv = m[0];
#pragma unroll
    for (int k = 1; k < 25; ++k) mxv = fmaxf(mxv, m[k]);
    float ss = 0.f;
#pragma unroll
    for (int k = 0; k < 25; ++k) { m[k] = __expf(m[k] - mxv); ss += m[k]; }
    float inv = 1.f / ss;
#pragma unroll
    for (int k = 0; k < 25; ++k) m[k] *= inv;
    int offs[25];
    unsigned vm = 0;
#pragma unroll
    for (int t = 0; t < 25; ++t) {
        int hh = h + t / 5 - 2, ww = w + t % 5 - 2;
        bool v = hh >= 0 && hh < 64 && ww >= 0 && ww < 64;
        offs[t] = v ? hh * 64 + ww : 0;
        if (v) vm |= 1u << t;
    }
    size_t outp = ((size_t)n * 256 * 128 + (2 * h + (ij >> 1))) * 128 + (2 * w + (ij & 1));
    for (int c = 0; c < 256; ++c) {
        const float* xc = xn + (size_t)c * 4096;
        float sum = 0.f;
#pragma unroll
        for (int t = 0; t < 25; ++t) {
            float v = ((vm >> t) & 1u) ? xc[offs[t]] : 0.f;
            sum += v * m[t];
        }
        out[outp + (size_t)c * 16384] = sum;
    }
}

extern "C" void kernel_launch(void* const* d_in, const int* in_sizes, int n_in,
                              void* d_out, int out_size, void* d_ws, size_t ws_size,
                              hipStream_t stream) {
    const float* x  = (const float*)d_in[0];
    const float* Wc = (const float*)d_in[1];
    const float* bc = (const float*)d_in[2];
    const float* We = (const float*)d_in[3];
    const float* be = (const float*)d_in[4];
    float* out = (float*)d_out;

    if (ws_size >= WS_NEED && d_ws != nullptr) {
        float* ws = (float*)d_ws;
        float* comp   = ws + COMP_F;
        float* wr     = ws + WR_F;
        float* logits = ws + LOG_F;
        hipLaunchKernelGGL(k0_wr,   dim3(289),  dim3(256), 0, stream, We, Wc, ws);
        hipLaunchKernelGGL(k1_comp, dim3(512),  dim3(256), 0, stream,
                           x, bc, /*wT=*/logits, comp);
        hipLaunchKernelGGL(k2_enc,  dim3(1280), dim3(256), 0, stream,
                           be, comp, wr, logits);
        hipLaunchKernelGGL(k2s_sm,  dim3(256),  dim3(256), 0, stream, logits);
        hipLaunchKernelGGL(k3_out,  dim3(1024), dim3(256), 0, stream,
                           x, logits, out);
    } else {
        hipLaunchKernelGGL(k_fused, dim3(256),  dim3(256), 0, stream,
                           x, Wc, bc, We, be, out);
    }
}

// Round 17
// 176.161 us; speedup vs baseline: 1.0050x; 1.0050x over previous
//
#include <hip/hip_runtime.h>
#include <hip/hip_bf16.h>

// CARAFE fp32 pipeline. x(4,256,64,64), Wc(64,256), bc(64), We(100,64,3,3),
// be(100) -> out(4,256,128,128). SF=2 K=5 G=1 CC=64 EK=3. All I/O fp32.
//
// ws layout (fp32 elements):
//   comp  [4][64][66*66]   zero-padded halo   @ 0          (1,115,136)
//   Wr2   [ij4][kt5][cc64][48]  q*5+kk packed @ 1,115,136  (61,440 of 64,512)
//   logit [tile256][e100][off64]  TILE-MAJOR, RAW (no softmax) @ 1,179,648
//     tile = n*64 + th*8 + tw (8x8-px k2 tiles), off = (h&7)*8 + (w&7).
//     NB: first 16,384 floats double as WcT[c256][cc64] during k0->k1.
// total 11,272,192 B. Host-gated on ws_size; fallback = fused kernel.
//
// Round 20 (this round): (a) REVERT k2 to the r15 best (stride 12, 47.1us,
// conflicts 0.26M -- r16's stride-10 was void: grid 1280 = exactly 5
// blocks/CU so the 6th block never existed, and conflicts returned 5.9M).
// (b) FUSE k2s INTO k3: softmax commutes with the contraction --
// out = (sum_k exp(l-mx) x_k) / (sum_k exp(l-mx)). k3 pass 1 computes
// per-ij max (100 coalesced scalar loads); the tap loop applies exp to
// its 4 mask scalars (+4 exp/tap on the trans pipe) and accumulates
// sm[4]; epilogue scales by rcp(sm). Deletes the k2s kernel, its launch
// gap, and its 13MB logits round-trip. Numerics: fp32-associativity only.

#define COMP_F 0
#define WR_F   1115136
#define LOG_F  1179648
#define WS_NEED 11272192ull
#define CSTR 4356  // 66*66 comp per-channel stride

// ---------------- K0: Wr2 repack + WcT transpose ------------------------
// job1 (tid < 57600): We(100,576) -> Wr2[ij][kt][cc][48], row = q*5+kk.
// job2 (tid >= 57600): Wc(64,256) -> WcT[c][cc] @ LOG_F (16,384 floats).
__global__ void k0_wr(const float* __restrict__ We, const float* __restrict__ Wc,
                      float* __restrict__ ws) {
    int tid = blockIdx.x * blockDim.x + threadIdx.x;
    if (tid < 57600) {
        int kk = tid % 5;
        int q  = (tid / 5) % 9;
        int cc = (tid / 45) % 64;
        int kt = (tid / 2880) % 5;
        int ij = tid / 14400;
        ws[WR_F + (size_t)(((ij * 5 + kt) * 64 + cc)) * 48 + q * 5 + kk] =
            We[(size_t)(4 * (kt * 5 + kk) + ij) * 576 + cc * 9 + q];
    } else if (tid < 57600 + 16384) {
        int t2 = tid - 57600;
        int c = t2 >> 6, cc = t2 & 63;
        ws[LOG_F + t2] = Wc[cc * 256 + c];
    }
}

// ---------------- K1 v4: 1x1 compressor 256->64, padded comp out --------
// grid 512 = ccq*64 + pxtile; block 256thr; thread = one pixel, 8 cc.
// Weights from WcT via s_load_dwordx8 (restrict args). Coalesced x loads.
__global__ __launch_bounds__(256) void k1_comp(const float* __restrict__ x,
                                               const float* __restrict__ bc,
                                               const float* __restrict__ wT,
                                               float* __restrict__ comp) {
    int b      = blockIdx.x;
    int pxtile = b & 63;       // 0..63 ; b%8 = pxtile%8 -> cc-siblings same XCD
    int ccq    = b >> 6;       // 0..7, wave-uniform
    int tid = threadIdx.x;
    int n   = pxtile >> 4;
    int off = (pxtile & 15) * 256 + tid;   // 0..4095 within image
    int h = off >> 6, w = off & 63;
    int cc0 = ccq * 8;

    const float* xp = x + (size_t)n * 256 * 4096 + off;

    float acc[8];
#pragma unroll
    for (int u = 0; u < 8; ++u) acc[u] = 0.f;

#pragma unroll 8
    for (int c = 0; c < 256; ++c) {
        float xv = xp[(size_t)c * 4096];
        const float* wr = wT + c * 64 + cc0;   // uniform -> s_load_dwordx8
#pragma unroll
        for (int u = 0; u < 8; ++u) acc[u] += xv * wr[u];
    }

    float* compb = comp + (size_t)(n * 64 + cc0) * CSTR;
#pragma unroll
    for (int u = 0; u < 8; ++u) {
        float* cb_ = compb + (size_t)u * CSTR;
        cb_[(h + 1) * 66 + (w + 1)] = acc[u] + bc[cc0 + u];
        // zero halo border (pad=1 of the 3x3 conv)
        if (w < 2) cb_[(h + 1) * 66 + (w ? 65 : 0)] = 0.f;
        if (h == 0)  { cb_[w] = 0.f;           if (w < 2) cb_[64 + w] = 0.f; }
        if (h == 63) { cb_[65 * 66 + w] = 0.f; if (w < 2) cb_[65 * 66 + 64 + w] = 0.f; }
    }
}

// ---------------- K2 v11: 3x3 encoder -> tile-major raw logits ----------
// r15 best config: 2-channel drain amortization, conflict-free lane map,
// SGPR weights, compT stride 12 (30720B, 5 blocks/CU, conflicts 0.26M),
// tile-major coalesced stores. grid 1280 = kt*256 + tile, (256,5).
__global__ __launch_bounds__(256, 5) void k2_enc(const float* __restrict__ be,
                                                 const float* __restrict__ comp,
                                                 const float* __restrict__ wr,
                                                 float* __restrict__ logits) {
    __shared__ __align__(16) float compT[64 * 120];  // 30720 B
    int b    = blockIdx.x;
    int tile = b & 255;                              // = n*64 + th*8 + tw
    int kt   = b >> 8;                               // 0..4, siblings same XCD
    int n = tile >> 6, th = (tile >> 3) & 7, tw = tile & 7;
    int h0 = th * 8, w0 = tw * 8;
    int tid = threadIdx.x;

    const float* compn = comp + (size_t)n * 64 * CSTR;
    // stage comp halo tile: compT[c*120 + r*12 + q] = comp[c][h0+r][w0+q]
    for (int e = tid; e < 6400; e += 256) {
        int c = e / 100, rq = e % 100, r = rq / 10, q = rq % 10;
        compT[c * 120 + r * 12 + q] =
            compn[(size_t)c * CSTR + (h0 + r) * 66 + (w0 + q)];
    }
    __syncthreads();

    int lane = tid & 63;
    int ij   = __builtin_amdgcn_readfirstlane(tid >> 6);  // force scalar
    int py = lane & 7, pxx = lane >> 3;   // conflict-free bank walk (r13)

    const float* wb = wr + (size_t)((ij * 5 + kt) * 64) * 48;

    float accA[5], accB[5];
#pragma unroll
    for (int kk = 0; kk < 5; ++kk) {
        accA[kk] = be[4 * (kt * 5 + kk) + ij];
        accB[kk] = 0.f;
    }

    for (int c = 0; c < 64; c += 2) {
        const float* cp = compT + c * 120 + py * 12 + pxx;
        float cv0[9], cv1[9];
#pragma unroll
        for (int dy = 0; dy < 3; ++dy)
#pragma unroll
            for (int dx = 0; dx < 3; ++dx) {
                cv0[dy * 3 + dx] = cp[dy * 12 + dx];
                cv1[dy * 3 + dx] = cp[120 + dy * 12 + dx];
            }
        const float* w0 = wb + c * 48;               // uniform -> s_load
        const float* w1 = w0 + 48;
#pragma unroll
        for (int q = 0; q < 9; ++q) {
            float v0 = cv0[q], v1 = cv1[q];
#pragma unroll
            for (int kk = 0; kk < 5; ++kk) {
                accA[kk] += v0 * w0[q * 5 + kk];     // v_fmac v, s, v
                accB[kk] += v1 * w1[q * 5 + kk];
            }
        }
    }

    // tile-major store: one contiguous 256B block per e-plane.
    float* lp = logits + (size_t)tile * 6400 + (py * 8 + pxx);
#pragma unroll
    for (int kk = 0; kk < 5; ++kk)
        lp[(4 * (kt * 5 + kk) + ij) * 64] = accA[kk] + accB[kk];
}

// ---------------- K3 v6: fused softmax + reassembly ---------------------
// grid 1024 x 256thr: b = cchunk*64 + tile16. 16x16 px tile, 16-c chunk.
// Consumes RAW logits: pass 1 computes per-ij max (100 coalesced scalar
// loads); tap loop applies exp(l - mx) to its 4 mask scalars (trans pipe)
// and accumulates sm[4] alongside A; epilogue scales by rcp(sm).
// out = (sum_k exp(l_k-mx) x_k) / (sum_k exp(l_k-mx))  ==  softmax-contract.
// x tile in LDS as [cg8][r20][q20][2] (unchanged, conflict-free b64).
__global__ __launch_bounds__(256) void k3_out(const float* __restrict__ x,
                                              const float* __restrict__ logits,
                                              float* __restrict__ out) {
    __shared__ __align__(16) float xt[8 * 20 * 42];  // 26880 B
    int b      = blockIdx.x;
    int tile16 = b & 63;
    int cchunk = b >> 6;
    int n = tile16 >> 4, ty0 = ((tile16 >> 2) & 3) * 16, tx0 = (tile16 & 3) * 16;
    int c0 = cchunk * 16;

    int py = threadIdx.x >> 4, pxx = threadIdx.x & 15;
    int h = ty0 + py, w = tx0 + pxx;

    // stage x halo tile as float2 (halo col origin tx0-2 is even -> the
    // 20-wide row is 10 aligned float2s, all-or-nothing in bounds).
    const float* xn = x + (size_t)(n * 256 + c0) * 4096;
    for (int e2 = threadIdx.x; e2 < 3200; e2 += 256) {
        int c = e2 / 200, rem = e2 % 200, r = rem / 10, q2 = rem % 10;
        int hh = ty0 + r - 2, ww = tx0 + 2 * q2 - 2;
        float2 v = {0.f, 0.f};
        if (hh >= 0 && hh < 64 && ww >= 0 && ww < 64)
            v = *(const float2*)(xn + (size_t)c * 4096 + hh * 64 + ww);
        int a0 = (c >> 1) * 840 + r * 42 + 4 * q2 + (c & 1);
        xt[a0]     = v.x;
        xt[a0 + 2] = v.y;
    }
    __syncthreads();

    // tile-major mask base for this thread's pixel
    int tileIdx = n * 64 + ((ty0 >> 3) + (py >> 3)) * 8 + (tx0 >> 3) + (pxx >> 3);
    int off     = (py & 7) * 8 + (pxx & 7);
    const float* mbase = logits + (size_t)tileIdx * 6400 + off;
    const float* vb = xt + py * 42 + pxx * 2;

    // pass 1: per-ij running max over the 25 taps (coalesced scalars)
    float4 mx = {mbase[0], mbase[64], mbase[128], mbase[192]};
#pragma unroll
    for (int t = 1; t < 25; ++t) {
        const float* mp = mbase + 4 * t * 64;
        mx.x = fmaxf(mx.x, mp[0]);   mx.y = fmaxf(mx.y, mp[64]);
        mx.z = fmaxf(mx.z, mp[128]); mx.w = fmaxf(mx.w, mp[192]);
    }

    float4 sm = {0.f, 0.f, 0.f, 0.f};
    float2 A[8][4];
#pragma unroll
    for (int cg = 0; cg < 8; ++cg)
#pragma unroll
        for (int u = 0; u < 4; ++u) A[cg][u] = {0.f, 0.f};

    for (int dy = 0; dy < 5; ++dy) {
        const float* vrow = vb + dy * 42;
#pragma unroll
        for (int dx = 0; dx < 5; ++dx) {
            int t = dy * 5 + dx;
            const float* mp = mbase + 4 * t * 64;
            float4 mk = {__expf(mp[0]   - mx.x), __expf(mp[64]  - mx.y),
                         __expf(mp[128] - mx.z), __expf(mp[192] - mx.w)};
            sm.x += mk.x; sm.y += mk.y; sm.z += mk.z; sm.w += mk.w;
#pragma unroll
            for (int cg = 0; cg < 8; ++cg) {
                float2 v = *(const float2*)(vrow + cg * 840 + dx * 2);
                A[cg][0].x += v.x * mk.x; A[cg][0].y += v.y * mk.x;
                A[cg][1].x += v.x * mk.y; A[cg][1].y += v.y * mk.y;
                A[cg][2].x += v.x * mk.z; A[cg][2].y += v.y * mk.z;
                A[cg][3].x += v.x * mk.w; A[cg][3].y += v.y * mk.w;
            }
        }
    }

    float4 iv = {1.f / sm.x, 1.f / sm.y, 1.f / sm.z, 1.f / sm.w};

#pragma unroll
    for (int cg = 0; cg < 8; ++cg) {
        int c = cg * 2;
        size_t ob0 = (((size_t)(n * 256 + c0 + c) * 128) + 2 * h) * 128 + 2 * w;
        float2 r0 = {A[cg][0].x * iv.x, A[cg][1].x * iv.y};
        float2 r1 = {A[cg][2].x * iv.z, A[cg][3].x * iv.w};
        *(float2*)(out + ob0)       = r0;
        *(float2*)(out + ob0 + 128) = r1;
        size_t ob1 = ob0 + 16384;
        float2 r2 = {A[cg][0].y * iv.x, A[cg][1].y * iv.y};
        float2 r3 = {A[cg][2].y * iv.z, A[cg][3].y * iv.w};
        *(float2*)(out + ob1)       = r2;
        *(float2*)(out + ob1 + 128) = r3;
    }
}

// ---------------- Fallback: fused kernel, fp32-only ---------------------
__global__ __launch_bounds__(256) void k_fused(const float* __restrict__ x,
                                               const float* __restrict__ Wc,
                                               const float* __restrict__ bc,
                                               const float* __restrict__ We,
                                               const float* __restrict__ be,
                                               float* __restrict__ out) {
    __shared__ float compS[64 * 101];
    int n = blockIdx.x >> 6, tile = blockIdx.x & 63;
    int ty0 = (tile >> 3) * 8, tx0 = (tile & 7) * 8;
    const float* xn = x + (size_t)n * 256 * 4096;
    {
        int pa = threadIdx.x & 127;
        int ga = __builtin_amdgcn_readfirstlane(threadIdx.x >> 7);
        bool act = pa < 100;
        int ah = ty0 + pa / 10 - 1, aw = tx0 + pa % 10 - 1;
        bool inb = act && ah >= 0 && ah < 64 && aw >= 0 && aw < 64;
        int xoff = ah * 64 + aw;
        float acc[32];
#pragma unroll
        for (int i = 0; i < 32; ++i) acc[i] = 0.f;
        for (int c = 0; c < 256; ++c) {
            float xv = inb ? xn[(size_t)c * 4096 + xoff] : 0.f;
#pragma unroll
            for (int i = 0; i < 32; ++i) acc[i] += xv * Wc[(ga * 32 + i) * 256 + c];
        }
        if (act)
#pragma unroll
            for (int i = 0; i < 32; ++i) {
                int cc = ga * 32 + i;
                compS[cc * 101 + pa] = inb ? acc[i] + bc[cc] : 0.f;
            }
    }
    __syncthreads();
    int px = threadIdx.x & 63;
    int ij = __builtin_amdgcn_readfirstlane(threadIdx.x >> 6);
    int py = px >> 3, pxx = px & 7;
    int h = ty0 + py, w = tx0 + pxx;
    float m[25];
#pragma unroll
    for (int k = 0; k < 25; ++k) m[k] = be[4 * k + ij];
    for (int cc = 0; cc < 64; ++cc) {
        float cv[9];
#pragma unroll
        for (int dy = 0; dy < 3; ++dy)
#pragma unroll
            for (int dx = 0; dx < 3; ++dx)
                cv[dy * 3 + dx] = compS[cc * 101 + (py + dy) * 10 + (pxx + dx)];
        int base = cc * 9;
#pragma unroll
        for (int k = 0; k < 25; ++k) {
            int eb = (4 * k + ij) * 576 + base;
            float s = 0.f;
#pragma unroll
            for (int qb = 0; qb < 9; ++qb) s += cv[qb] * We[eb + qb];
            m[k] += s;
        }
    }
    float mxv = m[0];
#pragma unroll
    for (int k = 1; k < 25; ++k) mxv = fmaxf(mxv, m[k]);
    float ss = 0.f;
#pragma unroll
    for (int k = 0; k < 25; ++k) { m[k] = __expf(m[k] - mxv); ss += m[k]; }
    float inv = 1.f / ss;
#pragma unroll
    for (int k = 0; k < 25; ++k) m[k] *= inv;
    int offs[25];
    unsigned vm = 0;
#pragma unroll
    for (int t = 0; t < 25; ++t) {
        int hh = h + t / 5 - 2, ww = w + t % 5 - 2;
        bool v = hh >= 0 && hh < 64 && ww >= 0 && ww < 64;
        offs[t] = v ? hh * 64 + ww : 0;
        if (v) vm |= 1u << t;
    }
    size_t outp = ((size_t)n * 256 * 128 + (2 * h + (ij >> 1))) * 128 + (2 * w + (ij & 1));
    for (int c = 0; c < 256; ++c) {
        const float* xc = xn + (size_t)c * 4096;
        float sum = 0.f;
#pragma unroll
        for (int t = 0; t < 25; ++t) {
            float v = ((vm >> t) & 1u) ? xc[offs[t]] : 0.f;
            sum += v * m[t];
        }
        out[outp + (size_t)c * 16384] = sum;
    }
}

extern "C" void kernel_launch(void* const* d_in, const int* in_sizes, int n_in,
                              void* d_out, int out_size, void* d_ws, size_t ws_size,
                              hipStream_t stream) {
    const float* x  = (const float*)d_in[0];
    const float* Wc = (const float*)d_in[1];
    const float* bc = (const float*)d_in[2];
    const float* We = (const float*)d_in[3];
    const float* be = (const float*)d_in[4];
    float* out = (float*)d_out;

    if (ws_size >= WS_NEED && d_ws != nullptr) {
        float* ws = (float*)d_ws;
        float* comp   = ws + COMP_F;
        float* wr     = ws + WR_F;
        float* logits = ws + LOG_F;
        hipLaunchKernelGGL(k0_wr,   dim3(289),  dim3(256), 0, stream, We, Wc, ws);
        hipLaunchKernelGGL(k1_comp, dim3(512),  dim3(256), 0, stream,
                           x, bc, /*wT=*/logits, comp);
        hipLaunchKernelGGL(k2_enc,  dim3(1280), dim3(256), 0, stream,
                           be, comp, wr, logits);
        hipLaunchKernelGGL(k3_out,  dim3(1024), dim3(256), 0, stream,
                           x, logits, out);
    } else {
        hipLaunchKernelGGL(k_fused, dim3(256),  dim3(256), 0, stream,
                           x, Wc, bc, We, be, out);
    }
}